// Round 22
// baseline (228.005 us; speedup 1.0000x reference)
//
#include <hip/hip_runtime.h>

typedef short bf16x8 __attribute__((ext_vector_type(8)));
typedef float f32x4 __attribute__((ext_vector_type(4)));
typedef unsigned int u32;
typedef unsigned short u16;

#define NIT 21
#define SMIN 1e-38f
#define CSH  140.0f    // constant exponent shift (r17/r21-validated numerics)
#define LDSCOL 136     // padded row stride in u16 (272B, 16B-aligned)

static __device__ __forceinline__ u16 f2bf(float f) {   // RNE pack (validated r8..r21)
    u32 u = __float_as_uint(f);
    u = (u + 0x7fffu + ((u >> 16) & 1u)) >> 16;
    return (u16)u;
}
static __device__ __forceinline__ float bf2f(u16 h) {
    return __uint_as_float(((u32)h) << 16);
}

// MFMA Sinkhorn, TWO matrices per 512-thread block (r21 structure, validated
// at 146.8us). r21 post-mortem: still barrier-bound (41 block barriers/matrix,
// no pipe >40%). With fragments AGPR-resident and LDS at 9.7KB, dual-matrix
// is now cheap (r19's failure was its 70KB LDS): +32 dw of MFMA-only AGPRs,
// SAME barrier count now covers 2 matrices, and each phase has 4 independent
// 2-deep MFMA chains. Per-matrix numerics byte-identical to r21: constant
// shift E = 2^(x*S-140) (streaming init), bf16 fragments, lazy rcp factors,
// m89 C/D layout, shared (lane,slot)->k map (HW k-permutation cancels).
__global__ __launch_bounds__(512)
void sinkhorn_kernel(const float* __restrict__ in, float* __restrict__ out) {
    const int t  = threadIdx.x;
    const int w  = t >> 6;         // wave 0..7
    const int lg = (t >> 4) & 3;   // k-group within wave
    const int ln = t & 15;         // m/n within tile
    const int M  = w * 16 + ln;    // this lane's owned row (af) and col (bf)
    const size_t mat0 = (size_t)(2 * blockIdx.x) << 14;
    const float S = 36.067376022224085f;   // (1/0.04)*log2(e)

    __shared__ __align__(16) u16 stage[32 * LDSCOL];   // 32-row transpose chunk (8.7KB)
    __shared__ __align__(16) u16 a_lds[2][128];
    __shared__ __align__(16) u16 b_lds[2][128];

    bf16x8 af[2][4];   // af[pm][c] = E_pm[M][c*32+lg*8 ..+7]   (A-operand)
    bf16x8 bf[2][4];   // bf[pm][c] = E_pm[c*32+lg*8 ..+7][M]   (B-operand)

    // ---- init per matrix: stream rows, E = bf16(2^(x*S-140)), a = rcp(rowsum) ----
#pragma unroll
    for (int pm = 0; pm < 2; ++pm) {
        const float* src = in + mat0 + ((size_t)pm << 14) + (size_t)M * 128 + lg * 8;
        float s = 0.f;
#pragma unroll
        for (int c = 0; c < 4; ++c) {
            float4 f0 = *(const float4*)(src + c * 32);
            float4 f1 = *(const float4*)(src + c * 32 + 4);
            float e0 = __builtin_amdgcn_exp2f(fmaf(f0.x, S, -CSH));
            float e1 = __builtin_amdgcn_exp2f(fmaf(f0.y, S, -CSH));
            float e2 = __builtin_amdgcn_exp2f(fmaf(f0.z, S, -CSH));
            float e3 = __builtin_amdgcn_exp2f(fmaf(f0.w, S, -CSH));
            float e4 = __builtin_amdgcn_exp2f(fmaf(f1.x, S, -CSH));
            float e5 = __builtin_amdgcn_exp2f(fmaf(f1.y, S, -CSH));
            float e6 = __builtin_amdgcn_exp2f(fmaf(f1.z, S, -CSH));
            float e7 = __builtin_amdgcn_exp2f(fmaf(f1.w, S, -CSH));
            s += ((e0 + e1) + (e2 + e3)) + ((e4 + e5) + (e6 + e7));
            bf16x8 fr;
            fr[0] = (short)f2bf(e0); fr[1] = (short)f2bf(e1);
            fr[2] = (short)f2bf(e2); fr[3] = (short)f2bf(e3);
            fr[4] = (short)f2bf(e4); fr[5] = (short)f2bf(e5);
            fr[6] = (short)f2bf(e6); fr[7] = (short)f2bf(e7);
            af[pm][c] = fr;
        }
        s += __shfl_xor(s, 16);   // row M held by lanes {ln,+16,+32,+48}
        s += __shfl_xor(s, 32);
        if (lg == 0) a_lds[pm][M] = f2bf(__builtin_amdgcn_rcpf(fmaxf(s, SMIN)));
    }

    // ---- build bf per matrix via 4 staged 32-row chunks (chunk q: waves 2q,2q+1) ----
#pragma unroll
    for (int pm = 0; pm < 2; ++pm) {
#pragma unroll
        for (int q = 0; q < 4; ++q) {
            __syncthreads();                // prior chunk's reads done / init visible
            if ((w >> 1) == q) {
                const int lr = ((w & 1) << 4) + ln;
#pragma unroll
                for (int c = 0; c < 4; ++c)
                    *(bf16x8*)&stage[lr * LDSCOL + c * 32 + lg * 8] = af[pm][c];
            }
            __syncthreads();
            bf16x8 fr;
#pragma unroll
            for (int j = 0; j < 8; ++j)     // k = q*32 + lg*8 + j, col = M
                fr[j] = (short)stage[(lg * 8 + j) * LDSCOL + M];
            bf[pm][q] = fr;
        }
    }
    __syncthreads();

    const f32x4 z4 = {0.f, 0.f, 0.f, 0.f};

#pragma unroll 1
    for (int it = 0; it < NIT; ++it) {
        // ---- col phase (both matrices): 4 independent 2-deep MFMA chains ----
        {
            bf16x8 p0 = *(const bf16x8*)&a_lds[0][lg * 8];
            bf16x8 p1 = *(const bf16x8*)&a_lds[0][32 + lg * 8];
            bf16x8 p2 = *(const bf16x8*)&a_lds[0][64 + lg * 8];
            bf16x8 p3 = *(const bf16x8*)&a_lds[0][96 + lg * 8];
            bf16x8 q0 = *(const bf16x8*)&a_lds[1][lg * 8];
            bf16x8 q1 = *(const bf16x8*)&a_lds[1][32 + lg * 8];
            bf16x8 q2 = *(const bf16x8*)&a_lds[1][64 + lg * 8];
            bf16x8 q3 = *(const bf16x8*)&a_lds[1][96 + lg * 8];
            f32x4 u0 = __builtin_amdgcn_mfma_f32_16x16x32_bf16(p0, bf[0][0], z4, 0, 0, 0);
            f32x4 u1 = __builtin_amdgcn_mfma_f32_16x16x32_bf16(p1, bf[0][1], z4, 0, 0, 0);
            f32x4 v0 = __builtin_amdgcn_mfma_f32_16x16x32_bf16(q0, bf[1][0], z4, 0, 0, 0);
            f32x4 v1 = __builtin_amdgcn_mfma_f32_16x16x32_bf16(q1, bf[1][1], z4, 0, 0, 0);
            u0 = __builtin_amdgcn_mfma_f32_16x16x32_bf16(p2, bf[0][2], u0, 0, 0, 0);
            u1 = __builtin_amdgcn_mfma_f32_16x16x32_bf16(p3, bf[0][3], u1, 0, 0, 0);
            v0 = __builtin_amdgcn_mfma_f32_16x16x32_bf16(q2, bf[1][2], v0, 0, 0, 0);
            v1 = __builtin_amdgcn_mfma_f32_16x16x32_bf16(q3, bf[1][3], v1, 0, 0, 0);
            if (lg == 0) {   // D rows identical; lane holds col n=M (m89 layout)
                b_lds[0][M] = f2bf(__builtin_amdgcn_rcpf(fmaxf(u0[0] + u1[0], SMIN)));
                b_lds[1][M] = f2bf(__builtin_amdgcn_rcpf(fmaxf(v0[0] + v1[0], SMIN)));
            }
        }
        __syncthreads();

        // ---- row phase (both matrices) ----
        if (it < NIT - 1) {
            bf16x8 p0 = *(const bf16x8*)&b_lds[0][lg * 8];
            bf16x8 p1 = *(const bf16x8*)&b_lds[0][32 + lg * 8];
            bf16x8 p2 = *(const bf16x8*)&b_lds[0][64 + lg * 8];
            bf16x8 p3 = *(const bf16x8*)&b_lds[0][96 + lg * 8];
            bf16x8 q0 = *(const bf16x8*)&b_lds[1][lg * 8];
            bf16x8 q1 = *(const bf16x8*)&b_lds[1][32 + lg * 8];
            bf16x8 q2 = *(const bf16x8*)&b_lds[1][64 + lg * 8];
            bf16x8 q3 = *(const bf16x8*)&b_lds[1][96 + lg * 8];
            f32x4 u0 = __builtin_amdgcn_mfma_f32_16x16x32_bf16(af[0][0], p0, z4, 0, 0, 0);
            f32x4 u1 = __builtin_amdgcn_mfma_f32_16x16x32_bf16(af[0][1], p1, z4, 0, 0, 0);
            f32x4 v0 = __builtin_amdgcn_mfma_f32_16x16x32_bf16(af[1][0], q0, z4, 0, 0, 0);
            f32x4 v1 = __builtin_amdgcn_mfma_f32_16x16x32_bf16(af[1][1], q1, z4, 0, 0, 0);
            u0 = __builtin_amdgcn_mfma_f32_16x16x32_bf16(af[0][2], p2, u0, 0, 0, 0);
            u1 = __builtin_amdgcn_mfma_f32_16x16x32_bf16(af[0][3], p3, u1, 0, 0, 0);
            v0 = __builtin_amdgcn_mfma_f32_16x16x32_bf16(af[1][2], q2, v0, 0, 0, 0);
            v1 = __builtin_amdgcn_mfma_f32_16x16x32_bf16(af[1][3], q3, v1, 0, 0, 0);
            if (ln == 0) {   // D cols identical; lane holds tile rows lg*4+r
#pragma unroll
                for (int r = 0; r < 4; ++r) {
                    a_lds[0][w * 16 + lg * 4 + r] =
                        f2bf(__builtin_amdgcn_rcpf(fmaxf(u0[r] + u1[r], SMIN)));
                    a_lds[1][w * 16 + lg * 4 + r] =
                        f2bf(__builtin_amdgcn_rcpf(fmaxf(v0[r] + v1[r], SMIN)));
                }
            }
            __syncthreads();
        }
    }

    // ---- epilogue per matrix: out = E * a_m * b_n ----
#pragma unroll
    for (int pm = 0; pm < 2; ++pm) {
        float* dst = out + mat0 + ((size_t)pm << 14) + (size_t)M * 128 + lg * 8;
        const float av = bf2f(a_lds[pm][M]);
#pragma unroll
        for (int c = 0; c < 4; ++c) {
            const bf16x8 e = af[pm][c];
            const bf16x8 bop = *(const bf16x8*)&b_lds[pm][c * 32 + lg * 8];
            float4 o0, o1;
            o0.x = bf2f((u16)e[0]) * av * bf2f((u16)bop[0]);
            o0.y = bf2f((u16)e[1]) * av * bf2f((u16)bop[1]);
            o0.z = bf2f((u16)e[2]) * av * bf2f((u16)bop[2]);
            o0.w = bf2f((u16)e[3]) * av * bf2f((u16)bop[3]);
            o1.x = bf2f((u16)e[4]) * av * bf2f((u16)bop[4]);
            o1.y = bf2f((u16)e[5]) * av * bf2f((u16)bop[5]);
            o1.z = bf2f((u16)e[6]) * av * bf2f((u16)bop[6]);
            o1.w = bf2f((u16)e[7]) * av * bf2f((u16)bop[7]);
            *(float4*)(dst + c * 32)     = o0;
            *(float4*)(dst + c * 32 + 4) = o1;
        }
    }
}

extern "C" void kernel_launch(void* const* d_in, const int* in_sizes, int n_in,
                              void* d_out, int out_size, void* d_ws, size_t ws_size,
                              hipStream_t stream) {
    (void)n_in; (void)d_ws; (void)ws_size; (void)out_size;
    const float* in  = (const float*)d_in[0];
    float*       out = (float*)d_out;
    const int n_mat = in_sizes[0] / (128 * 128);  // 4096
    sinkhorn_kernel<<<dim3(n_mat / 2), dim3(512), 0, stream>>>(in, out);
}

// Round 23
// 173.805 us; speedup vs baseline: 1.3118x; 1.3118x over previous
//
#include <hip/hip_runtime.h>

typedef short bf16x8 __attribute__((ext_vector_type(8)));
typedef float f32x4 __attribute__((ext_vector_type(4)));
typedef unsigned int u32;
typedef unsigned short u16;

#define NIT 21
#define SMIN 1e-38f
#define CSH  140.0f    // constant exponent shift (r17/r21-validated numerics)
#define LDSCOL 136     // padded row stride in u16 (272B, 16B-aligned)

static __device__ __forceinline__ u16 f2bf(float f) {   // RNE pack (validated r8..r21)
    u32 u = __float_as_uint(f);
    u = (u + 0x7fffu + ((u >> 16) & 1u)) >> 16;
    return (u16)u;
}
static __device__ __forceinline__ float bf2f(u16 h) {
    return __uint_as_float(((u32)h) << 16);
}

// MFMA Sinkhorn, 256 threads / 4 waves per 128x128 matrix.
// r21 (146.8us, validated) post-mortem: barrier-gap-bound with only 1.6
// 512-thread blocks/CU resident. Same per-wave state here (64 dw of MFMA-only
// AGPR fragments: af[2][4] row tiles + bf[2][4] col tiles = r14's validated
// wave geometry), but blocks are 4 waves -> 4 blocks/CU = 4 INDEPENDENT
// matrices per CU (vs 1.6): each SIMD hosts waves of 4 different matrices, so
// one block's barrier drain is filled by the other three. Barriers sync 4
// waves, not 8; each phase has 4 independent 2-deep MFMA chains.
// Numerics byte-identical to r21: E = bf16(2^(x*S-140)) streaming init, lazy
// rcp factors via 256B a/b LDS vectors, m89 C/D layout, both mfma operands
// share the (lane,slot)->k map (HW k-permutation cancels). Unified regs
// ~120 <= 128 budget; waves_per_eu(4,4) pins it (r12-proven safe band).
__global__ void __attribute__((amdgpu_flat_work_group_size(256, 256),
                               amdgpu_waves_per_eu(4, 4)))
sinkhorn_kernel(const float* __restrict__ in, float* __restrict__ out) {
    const int t  = threadIdx.x;
    const int w  = t >> 6;         // wave 0..3
    const int lg = (t >> 4) & 3;   // k-group within wave
    const int ln = t & 15;         // m/n within tile
    const size_t mat = (size_t)blockIdx.x << 14;
    const float S = 36.067376022224085f;   // (1/0.04)*log2(e)

    __shared__ __align__(16) u16 stage[32 * LDSCOL];   // 32-row transpose chunk (8.7KB)
    __shared__ __align__(16) u16 a_lds[128];
    __shared__ __align__(16) u16 b_lds[128];

    bf16x8 af[2][4];   // af[th][c] = E[w*32+th*16+ln][c*32+lg*8 ..+7]  (A-operand)
    bf16x8 bf[2][4];   // bf[uh][q] = E[q*32+lg*8 ..+7][w*32+uh*16+ln]  (B-operand)

    // ---- init: stream rows, E = bf16(2^(x*S-140)), a = rcp(rowsum) ----
#pragma unroll
    for (int th = 0; th < 2; ++th) {
        const int M = w * 32 + th * 16 + ln;
        const float* src = in + mat + (size_t)M * 128 + lg * 8;
        float s = 0.f;
#pragma unroll
        for (int c = 0; c < 4; ++c) {
            float4 f0 = *(const float4*)(src + c * 32);
            float4 f1 = *(const float4*)(src + c * 32 + 4);
            float e0 = __builtin_amdgcn_exp2f(fmaf(f0.x, S, -CSH));
            float e1 = __builtin_amdgcn_exp2f(fmaf(f0.y, S, -CSH));
            float e2 = __builtin_amdgcn_exp2f(fmaf(f0.z, S, -CSH));
            float e3 = __builtin_amdgcn_exp2f(fmaf(f0.w, S, -CSH));
            float e4 = __builtin_amdgcn_exp2f(fmaf(f1.x, S, -CSH));
            float e5 = __builtin_amdgcn_exp2f(fmaf(f1.y, S, -CSH));
            float e6 = __builtin_amdgcn_exp2f(fmaf(f1.z, S, -CSH));
            float e7 = __builtin_amdgcn_exp2f(fmaf(f1.w, S, -CSH));
            s += ((e0 + e1) + (e2 + e3)) + ((e4 + e5) + (e6 + e7));
            bf16x8 fr;
            fr[0] = (short)f2bf(e0); fr[1] = (short)f2bf(e1);
            fr[2] = (short)f2bf(e2); fr[3] = (short)f2bf(e3);
            fr[4] = (short)f2bf(e4); fr[5] = (short)f2bf(e5);
            fr[6] = (short)f2bf(e6); fr[7] = (short)f2bf(e7);
            af[th][c] = fr;
        }
        s += __shfl_xor(s, 16);   // row M held by lanes {ln,+16,+32,+48}
        s += __shfl_xor(s, 32);
        if (lg == 0) a_lds[M] = f2bf(__builtin_amdgcn_rcpf(fmaxf(s, SMIN)));
    }

    // ---- build bf via 4 staged 32-row chunks (chunk q owned by wave q) ----
#pragma unroll
    for (int q = 0; q < 4; ++q) {
        __syncthreads();                // prior chunk's reads done / init visible
        if (w == q) {
#pragma unroll
            for (int th = 0; th < 2; ++th) {
                const int lr = th * 16 + ln;
#pragma unroll
                for (int c = 0; c < 4; ++c)
                    *(bf16x8*)&stage[lr * LDSCOL + c * 32 + lg * 8] = af[th][c];
            }
        }
        __syncthreads();
#pragma unroll
        for (int uh = 0; uh < 2; ++uh) {
            const int N = w * 32 + uh * 16 + ln;
            bf16x8 fr;
#pragma unroll
            for (int j = 0; j < 8; ++j)     // k = q*32 + lg*8 + j, col = N
                fr[j] = (short)stage[(lg * 8 + j) * LDSCOL + N];
            bf[uh][q] = fr;
        }
    }

    const f32x4 z4 = {0.f, 0.f, 0.f, 0.f};

#pragma unroll 1
    for (int it = 0; it < NIT; ++it) {
        // ---- col phase: 4 independent 2-deep MFMA chains (cols w*32..+31) ----
        {
            bf16x8 a0 = *(const bf16x8*)&a_lds[lg * 8];      // broadcast reads
            bf16x8 a1 = *(const bf16x8*)&a_lds[32 + lg * 8];
            bf16x8 a2 = *(const bf16x8*)&a_lds[64 + lg * 8];
            bf16x8 a3 = *(const bf16x8*)&a_lds[96 + lg * 8];
            f32x4 x0 = __builtin_amdgcn_mfma_f32_16x16x32_bf16(a0, bf[0][0], z4, 0, 0, 0);
            f32x4 x1 = __builtin_amdgcn_mfma_f32_16x16x32_bf16(a1, bf[0][1], z4, 0, 0, 0);
            f32x4 y0 = __builtin_amdgcn_mfma_f32_16x16x32_bf16(a0, bf[1][0], z4, 0, 0, 0);
            f32x4 y1 = __builtin_amdgcn_mfma_f32_16x16x32_bf16(a1, bf[1][1], z4, 0, 0, 0);
            x0 = __builtin_amdgcn_mfma_f32_16x16x32_bf16(a2, bf[0][2], x0, 0, 0, 0);
            x1 = __builtin_amdgcn_mfma_f32_16x16x32_bf16(a3, bf[0][3], x1, 0, 0, 0);
            y0 = __builtin_amdgcn_mfma_f32_16x16x32_bf16(a2, bf[1][2], y0, 0, 0, 0);
            y1 = __builtin_amdgcn_mfma_f32_16x16x32_bf16(a3, bf[1][3], y1, 0, 0, 0);
            if (lg == 0) {   // D rows identical; lane holds col n (m89 layout)
                b_lds[w * 32 + ln]      = f2bf(__builtin_amdgcn_rcpf(fmaxf(x0[0] + x1[0], SMIN)));
                b_lds[w * 32 + 16 + ln] = f2bf(__builtin_amdgcn_rcpf(fmaxf(y0[0] + y1[0], SMIN)));
            }
        }
        __syncthreads();

        // ---- row phase: rows w*32..+31 ----
        if (it < NIT - 1) {
            bf16x8 b0 = *(const bf16x8*)&b_lds[lg * 8];
            bf16x8 b1 = *(const bf16x8*)&b_lds[32 + lg * 8];
            bf16x8 b2 = *(const bf16x8*)&b_lds[64 + lg * 8];
            bf16x8 b3 = *(const bf16x8*)&b_lds[96 + lg * 8];
            f32x4 u0 = __builtin_amdgcn_mfma_f32_16x16x32_bf16(af[0][0], b0, z4, 0, 0, 0);
            f32x4 u1 = __builtin_amdgcn_mfma_f32_16x16x32_bf16(af[0][1], b1, z4, 0, 0, 0);
            f32x4 v0 = __builtin_amdgcn_mfma_f32_16x16x32_bf16(af[1][0], b0, z4, 0, 0, 0);
            f32x4 v1 = __builtin_amdgcn_mfma_f32_16x16x32_bf16(af[1][1], b1, z4, 0, 0, 0);
            u0 = __builtin_amdgcn_mfma_f32_16x16x32_bf16(af[0][2], b2, u0, 0, 0, 0);
            u1 = __builtin_amdgcn_mfma_f32_16x16x32_bf16(af[0][3], b3, u1, 0, 0, 0);
            v0 = __builtin_amdgcn_mfma_f32_16x16x32_bf16(af[1][2], b2, v0, 0, 0, 0);
            v1 = __builtin_amdgcn_mfma_f32_16x16x32_bf16(af[1][3], b3, v1, 0, 0, 0);
            if (ln == 0) {   // D cols identical; lane holds tile rows lg*4+r
#pragma unroll
                for (int r = 0; r < 4; ++r) {
                    a_lds[w * 32 +      lg * 4 + r] =
                        f2bf(__builtin_amdgcn_rcpf(fmaxf(u0[r] + u1[r], SMIN)));
                    a_lds[w * 32 + 16 + lg * 4 + r] =
                        f2bf(__builtin_amdgcn_rcpf(fmaxf(v0[r] + v1[r], SMIN)));
                }
            }
            __syncthreads();
        }
    }

    // ---- epilogue: out = E * a_m * b_n ----
#pragma unroll
    for (int th = 0; th < 2; ++th) {
        const int M = w * 32 + th * 16 + ln;
        float* dst = out + mat + (size_t)M * 128 + lg * 8;
        const float av = bf2f(a_lds[M]);
#pragma unroll
        for (int c = 0; c < 4; ++c) {
            const bf16x8 e = af[th][c];
            const bf16x8 bop = *(const bf16x8*)&b_lds[c * 32 + lg * 8];
            float4 o0, o1;
            o0.x = bf2f((u16)e[0]) * av * bf2f((u16)bop[0]);
            o0.y = bf2f((u16)e[1]) * av * bf2f((u16)bop[1]);
            o0.z = bf2f((u16)e[2]) * av * bf2f((u16)bop[2]);
            o0.w = bf2f((u16)e[3]) * av * bf2f((u16)bop[3]);
            o1.x = bf2f((u16)e[4]) * av * bf2f((u16)bop[4]);
            o1.y = bf2f((u16)e[5]) * av * bf2f((u16)bop[5]);
            o1.z = bf2f((u16)e[6]) * av * bf2f((u16)bop[6]);
            o1.w = bf2f((u16)e[7]) * av * bf2f((u16)bop[7]);
            *(float4*)(dst + c * 32)     = o0;
            *(float4*)(dst + c * 32 + 4) = o1;
        }
    }
}

extern "C" void kernel_launch(void* const* d_in, const int* in_sizes, int n_in,
                              void* d_out, int out_size, void* d_ws, size_t ws_size,
                              hipStream_t stream) {
    (void)n_in; (void)d_ws; (void)ws_size; (void)out_size;
    const float* in  = (const float*)d_in[0];
    float*       out = (float*)d_out;
    const int n_mat = in_sizes[0] / (128 * 128);  // 4096
    sinkhorn_kernel<<<dim3(n_mat), dim3(256), 0, stream>>>(in, out);
}